// Round 9
// baseline (1005.481 us; speedup 1.0000x reference)
//
#include <hip/hip_runtime.h>
#include <hip/hip_bf16.h>
#include <math.h>
#include <type_traits>

// Problem constants
#define N_TOK 32768
#define DIMD  512
#define FFD   2048
#define NE    8
#define CAPQ  5120
#define TPE2  20          // CAPQ / 256 row-tiles per expert
#define NBLK  128         // scan blocks (256 tokens each)

typedef __attribute__((ext_vector_type(8))) short          bf16x8;
typedef __attribute__((ext_vector_type(4))) float          f32x4;
typedef __attribute__((ext_vector_type(8))) unsigned short u16x8;

__device__ __forceinline__ unsigned short f2bf(float f) {
  union { float f; unsigned u; } v; v.f = f;
  unsigned r = v.u + 0x7fffu + ((v.u >> 16) & 1u);   // RNE (finite values only)
  return (unsigned short)(r >> 16);
}

// tanh-gelu in sigmoid form: 0.5v(1+tanh u) == v * sigma(2u), exact identity.
__device__ __forceinline__ float gelu_f(float v) {
  float t = v * v;
  float q = fmaf(-0.0713548162f, t, -1.5957691216f);   // -2*(a + b*t)
  float w = v * q;                                      // -2u
  float d = 1.0f + __expf(w);
  return v * __builtin_amdgcn_rcpf(d);
}

// async global->LDS, 16B/lane; LDS dest is wave-uniform base + lane*16
#define GLL16(gsrc, ldst)                                                      \
  __builtin_amdgcn_global_load_lds(                                            \
      (const __attribute__((address_space(1))) void*)(gsrc),                   \
      (__attribute__((address_space(3))) void*)(ldst), 16, 0, 0)

// ---- merged tiled transpose + f32->bf16: 17 slabs (1 shared + 8 + 8) -----
__global__ __launch_bounds__(256) void transpose_cvt3_kernel(
    const float* __restrict__ s0, const float* __restrict__ s1,
    const float* __restrict__ s2,
    unsigned short* __restrict__ d0, unsigned short* __restrict__ d1,
    unsigned short* __restrict__ d2, int R, int C) {
  __shared__ unsigned short tile[32][33];
  const int z = blockIdx.z;
  const float* in; unsigned short* out;
  if (z == 0)      { in = s0;                            out = d0; }
  else if (z <= 8) { in = s1 + (size_t)(z - 1) * R * C;  out = d1 + (size_t)(z - 1) * R * C; }
  else             { in = s2 + (size_t)(z - 9) * R * C;  out = d2 + (size_t)(z - 9) * R * C; }
  int c0 = blockIdx.x * 32, r0 = blockIdx.y * 32;
  int tx = threadIdx.x & 31, ty = threadIdx.x >> 5;   // 32x8
  #pragma unroll
  for (int i = 0; i < 4; i++) {
    int r = ty + i * 8;
    tile[r][tx] = f2bf(in[(size_t)(r0 + r) * C + c0 + tx]);
  }
  __syncthreads();
  #pragma unroll
  for (int i = 0; i < 4; i++) {
    int c = ty + i * 8;
    out[(size_t)(c0 + c) * R + r0 + tx] = tile[tx][c];
  }
}

// ---- router: logits, softmax, top-1, gate (both banks) + x->bf16 fused ---
__global__ __launch_bounds__(256) void router_kernel(
    const float* __restrict__ x, unsigned short* __restrict__ xb,
    const float* __restrict__ WrS, const float* __restrict__ brS,
    const float* __restrict__ WrF, const float* __restrict__ brF,
    int* __restrict__ expS, float* __restrict__ gateS,
    int* __restrict__ expF, float* __restrict__ gateF) {
  __shared__ float wS[DIMD * NE], wF[DIMD * NE];
  for (int i = threadIdx.x; i < DIMD * NE / 4; i += 256) {
    ((float4*)wS)[i] = ((const float4*)WrS)[i];
    ((float4*)wF)[i] = ((const float4*)WrF)[i];
  }
  __syncthreads();
  const int w = threadIdx.x >> 6, lane = threadIdx.x & 63;
  const int n0 = (blockIdx.x * 4 + w) * 8;       // 8 tokens per wave
  for (int t = 0; t < 8; t++) {
    const int n = n0 + t;
    const float* xr = x + (size_t)n * DIMD + lane * 8;
    float4 xa = *(const float4*)xr, xb4 = *(const float4*)(xr + 4);
    float xv[8] = {xa.x, xa.y, xa.z, xa.w, xb4.x, xb4.y, xb4.z, xb4.w};
    u16x8 xo;
    #pragma unroll
    for (int j = 0; j < 8; j++) xo[j] = f2bf(xv[j]);
    *(u16x8*)(xb + (size_t)n * DIMD + lane * 8) = xo;   // fused x->bf16
    float aS[NE], aF[NE];
    #pragma unroll
    for (int e = 0; e < NE; e++) { aS[e] = 0.f; aF[e] = 0.f; }
    #pragma unroll
    for (int j = 0; j < 8; j++) {
      const int k = lane * 8 + j;
      const float* ps = &wS[k * NE];
      const float* pf = &wF[k * NE];
      #pragma unroll
      for (int e = 0; e < NE; e++) { aS[e] += xv[j] * ps[e]; aF[e] += xv[j] * pf[e]; }
    }
    #pragma unroll
    for (int e = 0; e < NE; e++)
      for (int off = 32; off; off >>= 1) {
        aS[e] += __shfl_xor(aS[e], off);
        aF[e] += __shfl_xor(aF[e], off);
      }
    if (lane == 0) {
      float l[NE];
      #pragma unroll
      for (int e = 0; e < NE; e++) l[e] = aS[e] + brS[e];
      float m = l[0]; int am = 0;
      #pragma unroll
      for (int e = 1; e < NE; e++) if (l[e] > m) { m = l[e]; am = e; }  // first max
      float s = 0.f;
      #pragma unroll
      for (int e = 0; e < NE; e++) s += __expf(l[e] - m);
      expS[n] = am; gateS[n] = __builtin_amdgcn_rcpf(s);
      #pragma unroll
      for (int e = 0; e < NE; e++) l[e] = aF[e] + brF[e];
      m = l[0]; am = 0;
      #pragma unroll
      for (int e = 1; e < NE; e++) if (l[e] > m) { m = l[e]; am = e; }
      s = 0.f;
      #pragma unroll
      for (int e = 0; e < NE; e++) s += __expf(l[e] - m);
      expF[n] = am; gateF[n] = __builtin_amdgcn_rcpf(s);
    }
  }
}

// ------------- parallel stable capacity scan (3 kernels) ------------------
__global__ __launch_bounds__(256) void scan_count_kernel(
    const int* __restrict__ expS, const int* __restrict__ expF,
    int* __restrict__ blockcnt) {
  const int b = blockIdx.x, t = threadIdx.x;
  const int w = t >> 6, lane = t & 63;
  const int eS_ = expS[b * 256 + t], eF_ = expF[b * 256 + t];
  __shared__ int cnt[2][4][NE];
  #pragma unroll
  for (int q = 0; q < NE; q++) {
    unsigned long long mS = __ballot(eS_ == q);
    unsigned long long mF = __ballot(eF_ == q);
    if (lane == 0) { cnt[0][w][q] = __popcll(mS); cnt[1][w][q] = __popcll(mF); }
  }
  __syncthreads();
  if (t < 16) {
    const int bank = t >> 3, q = t & 7;
    blockcnt[bank * NBLK * NE + b * NE + q] =
        cnt[bank][0][q] + cnt[bank][1][q] + cnt[bank][2][q] + cnt[bank][3][q];
  }
}

// meta layout: [cntS 8][hbS 8][cntF 8][hbF 8]; hidden bases 256-aligned
__global__ __launch_bounds__(64) void scan_base_kernel(
    const int* __restrict__ blockcnt, int* __restrict__ blockbase,
    int* __restrict__ meta) {
  __shared__ int tot[2][NE];
  const int t = threadIdx.x;
  if (t < 16) {
    const int bank = t >> 3, q = t & 7;
    int run = 0;
    for (int i = 0; i < NBLK; i++) {
      int v = blockcnt[bank * NBLK * NE + i * NE + q];
      blockbase[bank * NBLK * NE + i * NE + q] = run;
      run += v;
    }
    tot[bank][q] = run;
  }
  __syncthreads();
  if (t == 0) {
    int hb_ = 0;
    for (int q = 0; q < NE; q++) {
      int cc = tot[0][q]; if (cc > CAPQ) cc = CAPQ;
      meta[q] = cc; meta[NE + q] = hb_;
      hb_ += ((cc + 255) >> 8) << 8;
    }
    hb_ = 0;
    for (int q = 0; q < NE; q++) {
      int cc = tot[1][q]; if (cc > CAPQ) cc = CAPQ;
      meta[2 * NE + q] = cc; meta[3 * NE + q] = hb_;
      hb_ += ((cc + 255) >> 8) << 8;
    }
  }
}

__global__ __launch_bounds__(256) void scan_write_kernel(
    const int* __restrict__ expS, const int* __restrict__ expF,
    const int* __restrict__ blockbase,
    int* __restrict__ idxS, int* __restrict__ idxF) {
  const int b = blockIdx.x, t = threadIdx.x;
  const int w = t >> 6, lane = t & 63;
  const int n = b * 256 + t;
  const int eS_ = expS[n], eF_ = expF[n];
  __shared__ int wcnt[2][4][NE];
  const unsigned long long ltmask = ((unsigned long long)1 << lane) - 1;
  int rS = 0, rF = 0;
  #pragma unroll
  for (int q = 0; q < NE; q++) {
    unsigned long long mS = __ballot(eS_ == q);
    unsigned long long mF = __ballot(eF_ == q);
    if (eS_ == q) rS = __popcll(mS & ltmask);
    if (eF_ == q) rF = __popcll(mF & ltmask);
    if (lane == 0) { wcnt[0][w][q] = __popcll(mS); wcnt[1][w][q] = __popcll(mF); }
  }
  __syncthreads();
  int pS = blockbase[0 * NBLK * NE + b * NE + eS_] + rS;
  int pF = blockbase[1 * NBLK * NE + b * NE + eF_] + rF;
  #pragma unroll
  for (int wv = 0; wv < 4; wv++) {
    if (wv < w) { pS += wcnt[0][wv][eS_]; pF += wcnt[1][wv][eF_]; }
  }
  if (pS < CAPQ) idxS[eS_ * CAPQ + pS] = n;
  if (pF < CAPQ) idxF[eF_ * CAPQ + pF] = n;
}

// --- MFMA GEMM: 256x256 tile, BK=32, FOUR LDS tile-buffers, fine phases ---
// 8 waves (2M x 4N), per-wave 128x64, acc[8][4]. Per K-tile: 2 phases x
// {ds_read frags; 2 GLL16 of tile t+3; [tile end: counted vmcnt(8)];
//  barrier; lgkmcnt(0)+sched_barrier; setprio(1) 16 MFMA setprio(0); barrier}.
// Stages at tile t target buf (t+3)&3 = (t-1)&3, freed at tile t-1's close
// barrier -> race-free by construction. vmcnt gate for tile t+1 allows
// exactly tiles t+2,t+3 (8 loads/thread); tail peels 4 -> 0 -> none.
// BK=32 swizzle: stored chunk position = chunk ^ ((row>>1)&3) (involution,
// both-sides: pre-swizzled GLL source + swizzled ds_read).
template <int EPI, bool GATHER, bool BANKED>
__global__ __launch_bounds__(512, 2) void gemm_kernel(
    const unsigned short* __restrict__ A,
    const unsigned short* __restrict__ Bt,   // [(e)][NC][K] bf16 (pre-transposed)
    const float* __restrict__ bias,          // [(e)][NC]
    const int* __restrict__ idx, const int* __restrict__ cnt,
    const int* __restrict__ hb, const float* __restrict__ gate,
    unsigned short* __restrict__ hidOut, float* __restrict__ fOut) {
  constexpr int K  = (EPI == 0) ? DIMD : FFD;
  constexpr int NC = (EPI == 0) ? FFD : DIMD;
  constexpr int NT = K / 32;                  // 16 (FFN1) or 64 (FFN2)

  __shared__ __align__(16) unsigned short sA[4][256 * 32];  // 4 x 16 KiB
  __shared__ __align__(16) unsigned short sB[4][256 * 32];  // 4 x 16 KiB

  const int tid = threadIdx.x;
  const int w = tid >> 6, lane = tid & 63;

  // bijective XCD-chunked block swizzle (m204)
  const int gx = gridDim.x;
  const int nwg = gx * gridDim.y;
  int flat = blockIdx.y * gx + blockIdx.x;
  {
    const int q8 = nwg >> 3, r8 = nwg & 7;
    const int xcd = flat & 7, loc = flat >> 3;
    flat = (xcd < r8 ? xcd * (q8 + 1) : r8 * (q8 + 1) + (xcd - r8) * q8) + loc;
  }
  const int bx = flat % gx, by = flat / gx;

  int e = 0, r0, cnte = 0;
  if (BANKED) {
    e = by / TPE2;
    r0 = (by - e * TPE2) * 256;
    cnte = cnt[e];
    if (r0 >= cnte) return;
  } else {
    r0 = by * 256;
  }

  // --- stage sources: thread covers rows {srow0, srow0+128}, 16B chunk gch
  const int srow0 = tid >> 2;                       // 0..127
  const int gch = (tid & 3) ^ ((tid >> 3) & 3);     // pre-swizzled source chunk
  const unsigned short* aS[2];
  const unsigned short* bS[2];
  const size_t bcol0 = (size_t)(BANKED ? e * NC : 0) + (size_t)bx * 256;
  #pragma unroll
  for (int i = 0; i < 2; i++) {
    const int r = i * 128 + srow0;
    size_t arow;
    if (GATHER) {
      int s = r0 + r;
      int tok = (s < cnte) ? idx[e * CAPQ + s] : 0;
      arow = (size_t)tok;
    } else if (BANKED) {
      arow = (size_t)(hb[e] + r0 + r);
    } else {
      arow = (size_t)(r0 + r);
    }
    aS[i] = A + arow * K + gch * 8;
    bS[i] = Bt + (bcol0 + r) * K + gch * 8;
  }

  // --- per-wave read bases (compile-time frag offsets from these)
  const int wr = w >> 2, wc = w & 3;                // wave: rows wr*128, cols wc*64
  const int grp = lane >> 4, l15 = lane & 15;
  const int kch = grp ^ ((l15 >> 1) & 3);           // swizzled k-chunk
  const int aBase = (wr * 128 + l15) * 32 + kch * 8;  // ushort index
  const int bBase = (wc * 64 + l15) * 32 + kch * 8;

  f32x4 acc[8][4];
  #pragma unroll
  for (int m = 0; m < 8; m++)
    #pragma unroll
    for (int n = 0; n < 4; n++) acc[m][n] = (f32x4){0.f, 0.f, 0.f, 0.f};

  bf16x8 af[4], bfr[4];

  auto stageA = [&](int sbuf, int kt) {
    char* d = (char*)&sA[sbuf][0] + (unsigned)w * 1024;
    const int off = kt * 32;
    GLL16(aS[0] + off, d);
    GLL16(aS[1] + off, d + 8192);
  };
  auto stageB = [&](int sbuf, int kt) {
    char* d = (char*)&sB[sbuf][0] + (unsigned)w * 1024;
    const int off = kt * 32;
    GLL16(bS[0] + off, d);
    GLL16(bS[1] + off, d + 8192);
  };

  // one K-tile: buffer bi; optionally stage tile kt3 into buf sbuf; vmcnt VM
  auto tile = [&](int bi, int sbuf, int kt3, auto STG, auto VM) {
    const unsigned short* A_ = &sA[bi][0];
    const unsigned short* B_ = &sB[bi][0];
    // ---- phase 0: m0-3 x n0-3 (reads A quad 0 + all B)
    #pragma unroll
    for (int mi = 0; mi < 4; mi++) af[mi] = *(const bf16x8*)&A_[aBase + mi * 512];
    #pragma unroll
    for (int n = 0; n < 4; n++) bfr[n] = *(const bf16x8*)&B_[bBase + n * 512];
    if constexpr (decltype(STG)::value) stageA(sbuf, kt3);
    __builtin_amdgcn_s_barrier();
    asm volatile("s_waitcnt lgkmcnt(0)" ::: "memory");
    __builtin_amdgcn_sched_barrier(0);
    __builtin_amdgcn_s_setprio(1);
    #pragma unroll
    for (int mi = 0; mi < 4; mi++)
      #pragma unroll
      for (int n = 0; n < 4; n++)
        acc[mi][n] = __builtin_amdgcn_mfma_f32_16x16x32_bf16(af[mi], bfr[n], acc[mi][n], 0, 0, 0);
    __builtin_amdgcn_s_setprio(0);
    __builtin_amdgcn_sched_barrier(0);
    __builtin_amdgcn_s_barrier();
    // ---- phase 1: m4-7 x n0-3 (B held in regs)
    #pragma unroll
    for (int mi = 0; mi < 4; mi++) af[mi] = *(const bf16x8*)&A_[aBase + (4 + mi) * 512];
    if constexpr (decltype(STG)::value) stageB(sbuf, kt3);
    if constexpr (decltype(VM)::value == 8)
      asm volatile("s_waitcnt vmcnt(8)" ::: "memory");
    else if constexpr (decltype(VM)::value == 4)
      asm volatile("s_waitcnt vmcnt(4)" ::: "memory");
    else if constexpr (decltype(VM)::value == 0)
      asm volatile("s_waitcnt vmcnt(0)" ::: "memory");
    __builtin_amdgcn_s_barrier();
    asm volatile("s_waitcnt lgkmcnt(0)" ::: "memory");
    __builtin_amdgcn_sched_barrier(0);
    __builtin_amdgcn_s_setprio(1);
    #pragma unroll
    for (int mi = 0; mi < 4; mi++)
      #pragma unroll
      for (int n = 0; n < 4; n++)
        acc[4 + mi][n] = __builtin_amdgcn_mfma_f32_16x16x32_bf16(af[mi], bfr[n], acc[4 + mi][n], 0, 0, 0);
    __builtin_amdgcn_s_setprio(0);
    __builtin_amdgcn_sched_barrier(0);
    __builtin_amdgcn_s_barrier();      // close: publishes gated tile, frees bi
  };

  // prologue: stage tiles 0,1,2 (12 loads); gate tile 0 (tiles 1,2 stay out)
  stageA(0, 0); stageB(0, 0);
  stageA(1, 1); stageB(1, 1);
  stageA(2, 2); stageB(2, 2);
  asm volatile("s_waitcnt vmcnt(8)" ::: "memory");
  __builtin_amdgcn_s_barrier();

  #pragma unroll 1
  for (int t = 0; t < NT - 3; ++t)
    tile(t & 3, (t + 3) & 3, t + 3, std::true_type{}, std::integral_constant<int, 8>{});
  tile((NT - 3) & 3, 0, 0, std::false_type{}, std::integral_constant<int, 4>{});
  tile((NT - 2) & 3, 0, 0, std::false_type{}, std::integral_constant<int, 0>{});
  tile((NT - 1) & 3, 0, 0, std::false_type{}, std::integral_constant<int, -1>{});

  // --- epilogue: C/D layout col=lane&15, row=(lane>>4)*4+j (m89-verified)
  const int grp4 = grp * 4;
  if constexpr (EPI == 0) {
    const size_t hrow0 = (size_t)((BANKED ? hb[e] : 0) + r0);
    const float* bP2 = bias + (BANKED ? e * NC : 0) + bx * 256;
    #pragma unroll
    for (int m = 0; m < 8; m++)
      #pragma unroll
      for (int j = 0; j < 4; j++) {
        const int rloc = wr * 128 + m * 16 + grp4 + j;
        unsigned short* hrow = hidOut + (hrow0 + rloc) * FFD + bx * 256;
        #pragma unroll
        for (int n = 0; n < 4; n++) {
          const int cloc = wc * 64 + n * 16 + l15;
          float v = acc[m][n][j] + bP2[cloc];
          hrow[cloc] = f2bf(gelu_f(v));
        }
      }
  } else if constexpr (EPI == 1) {
    const float* bP2 = bias + bx * 256;
    #pragma unroll
    for (int m = 0; m < 8; m++)
      #pragma unroll
      for (int j = 0; j < 4; j++) {
        const int rloc = wr * 128 + m * 16 + grp4 + j;
        float* orow = fOut + (size_t)(r0 + rloc) * DIMD + bx * 256;
        #pragma unroll
        for (int n = 0; n < 4; n++) {
          const int cloc = wc * 64 + n * 16 + l15;
          orow[cloc] = acc[m][n][j] + bP2[cloc];
        }
      }
  } else {
    const float* bP2 = bias + e * NC + bx * 256;
    const int* idxe = idx + e * CAPQ + r0;
    #pragma unroll
    for (int m = 0; m < 8; m++)
      #pragma unroll
      for (int j = 0; j < 4; j++) {
        const int rloc = wr * 128 + m * 16 + grp4 + j;
        if (r0 + rloc < cnte) {
          const int tok = idxe[rloc];
          const float gv = gate[tok];
          float* orow = fOut + (size_t)tok * DIMD + bx * 256;
          #pragma unroll
          for (int n = 0; n < 4; n++) {
            const int cloc = wc * 64 + n * 16 + l15;
            orow[cloc] += (acc[m][n][j] + bP2[cloc]) * gv;  // unique (tok,col)
          }
        }
      }
  }
}

extern "C" void kernel_launch(void* const* d_in, const int* in_sizes, int n_in,
                              void* d_out, int out_size, void* d_ws, size_t ws_size,
                              hipStream_t stream) {
  const float* x   = (const float*)d_in[0];
  const float* WrS = (const float*)d_in[1];
  const float* brS = (const float*)d_in[2];
  const float* WrF = (const float*)d_in[3];
  const float* brF = (const float*)d_in[4];
  const float* Ws1 = (const float*)d_in[5];
  const float* bs1 = (const float*)d_in[6];
  const float* Ws2 = (const float*)d_in[7];
  const float* bs2 = (const float*)d_in[8];
  const float* W1s = (const float*)d_in[9];
  const float* b1s = (const float*)d_in[10];
  const float* W2s = (const float*)d_in[11];
  const float* b2s = (const float*)d_in[12];
  const float* W1f = (const float*)d_in[13];
  const float* b1f = (const float*)d_in[14];
  const float* W2f = (const float*)d_in[15];
  const float* b2f = (const float*)d_in[16];
  float* out = (float*)d_out;

  char* ws = (char*)d_ws;
  size_t off = 0;
  auto alloc = [&](size_t b) { char* p = ws + off; off += (b + 255) & ~(size_t)255; return p; };
  unsigned short* xb     = (unsigned short*)alloc((size_t)N_TOK * DIMD * 2);
  unsigned short* ws1t   = (unsigned short*)alloc((size_t)FFD * DIMD * 2);
  unsigned short* ws2t   = (unsigned short*)alloc((size_t)DIMD * FFD * 2);
  unsigned short* w1st   = (unsigned short*)alloc((size_t)NE * FFD * DIMD * 2);
  unsigned short* w2st   = (unsigned short*)alloc((size_t)NE * DIMD * FFD * 2);
  unsigned short* w1ft   = (unsigned short*)alloc((size_t)NE * FFD * DIMD * 2);
  unsigned short* w2ft   = (unsigned short*)alloc((size_t)NE * DIMD * FFD * 2);
  unsigned short* hidden = (unsigned short*)alloc((size_t)(N_TOK + NE * 256) * FFD * 2);
  int*   expS = (int*)alloc((size_t)N_TOK * 4);
  int*   expF = (int*)alloc((size_t)N_TOK * 4);
  float* gS   = (float*)alloc((size_t)N_TOK * 4);
  float* gF   = (float*)alloc((size_t)N_TOK * 4);
  int*   idxS = (int*)alloc((size_t)NE * CAPQ * 4);
  int*   idxF = (int*)alloc((size_t)NE * CAPQ * 4);
  int*   meta = (int*)alloc(4 * NE * 4);
  int*   blockcnt  = (int*)alloc((size_t)2 * NBLK * NE * 4);
  int*   blockbase = (int*)alloc((size_t)2 * NBLK * NE * 4);
  if (off > ws_size) return;   // ws too small -> will fail validation

  int* cntS = meta;           int* hbS = meta + NE;
  int* cntF = meta + 2 * NE;  int* hbF = meta + 3 * NE;

  // merged weight transposes (2 launches instead of 6)
  transpose_cvt3_kernel<<<dim3(FFD / 32, DIMD / 32, 17), 256, 0, stream>>>(
      Ws1, W1s, W1f, ws1t, w1st, w1ft, DIMD, FFD);
  transpose_cvt3_kernel<<<dim3(DIMD / 32, FFD / 32, 17), 256, 0, stream>>>(
      Ws2, W2s, W2f, ws2t, w2st, w2ft, FFD, DIMD);
  router_kernel<<<N_TOK / 32, 256, 0, stream>>>(x, xb, WrS, brS, WrF, brF, expS, gS, expF, gF);
  scan_count_kernel<<<NBLK, 256, 0, stream>>>(expS, expF, blockcnt);
  scan_base_kernel<<<1, 64, 0, stream>>>(blockcnt, blockbase, meta);
  scan_write_kernel<<<NBLK, 256, 0, stream>>>(expS, expF, blockbase, idxS, idxF);

  // shared FFN (writes all of out)
  gemm_kernel<0, false, false><<<dim3(FFD / 256, N_TOK / 256), 512, 0, stream>>>(
      xb, ws1t, bs1, nullptr, nullptr, nullptr, nullptr, hidden, nullptr);
  gemm_kernel<1, false, false><<<dim3(DIMD / 256, N_TOK / 256), 512, 0, stream>>>(
      hidden, ws2t, bs2, nullptr, nullptr, nullptr, nullptr, nullptr, out);
  // spatial bank (adds into out)
  gemm_kernel<0, true, true><<<dim3(FFD / 256, NE * TPE2), 512, 0, stream>>>(
      xb, w1st, b1s, idxS, cntS, hbS, nullptr, hidden, nullptr);
  gemm_kernel<2, false, true><<<dim3(DIMD / 256, NE * TPE2), 512, 0, stream>>>(
      hidden, w2st, b2s, idxS, cntS, hbS, gS, nullptr, out);
  // spectral bank (adds into out)
  gemm_kernel<0, true, true><<<dim3(FFD / 256, NE * TPE2), 512, 0, stream>>>(
      xb, w1ft, b1f, idxF, cntF, hbF, nullptr, hidden, nullptr);
  gemm_kernel<2, false, true><<<dim3(DIMD / 256, NE * TPE2), 512, 0, stream>>>(
      hidden, w2ft, b2f, idxF, cntF, hbF, gF, nullptr, out);
}

// Round 10
// 856.722 us; speedup vs baseline: 1.1736x; 1.1736x over previous
//
#include <hip/hip_runtime.h>
#include <hip/hip_bf16.h>
#include <math.h>

// Problem constants
#define N_TOK 32768
#define DIMD  512
#define FFD   2048
#define NE    8
#define CAPQ  5120
#define TPE   40          // CAPQ / 128 row-tiles per expert
#define NBLK  128         // scan blocks (256 tokens each)

typedef __attribute__((ext_vector_type(8))) short          bf16x8;
typedef __attribute__((ext_vector_type(4))) float          f32x4;
typedef __attribute__((ext_vector_type(8))) unsigned short u16x8;

__device__ __forceinline__ unsigned short f2bf(float f) {
  union { float f; unsigned u; } v; v.f = f;
  unsigned r = v.u + 0x7fffu + ((v.u >> 16) & 1u);   // RNE (finite values only)
  return (unsigned short)(r >> 16);
}

// tanh-gelu in sigmoid form: 0.5v(1+tanh u) == v * sigma(2u), exact identity.
__device__ __forceinline__ float gelu_f(float v) {
  float t = v * v;
  float q = fmaf(-0.0713548162f, t, -1.5957691216f);   // -2*(a + b*t)
  float w = v * q;                                      // -2u
  float d = 1.0f + __expf(w);
  return v * __builtin_amdgcn_rcpf(d);
}

// async global->LDS, 16B/lane; LDS dest is wave-uniform base + lane*16
#define GLL16(gsrc, ldst)                                                      \
  __builtin_amdgcn_global_load_lds(                                            \
      (const __attribute__((address_space(1))) void*)(gsrc),                   \
      (__attribute__((address_space(3))) void*)(ldst), 16, 0, 0)

// ---- merged tiled transpose + f32->bf16: 17 slabs (1 shared + 8 + 8) -----
__global__ __launch_bounds__(256) void transpose_cvt3_kernel(
    const float* __restrict__ s0, const float* __restrict__ s1,
    const float* __restrict__ s2,
    unsigned short* __restrict__ d0, unsigned short* __restrict__ d1,
    unsigned short* __restrict__ d2, int R, int C) {
  __shared__ unsigned short tile[32][33];
  const int z = blockIdx.z;
  const float* in; unsigned short* out;
  if (z == 0)      { in = s0;                            out = d0; }
  else if (z <= 8) { in = s1 + (size_t)(z - 1) * R * C;  out = d1 + (size_t)(z - 1) * R * C; }
  else             { in = s2 + (size_t)(z - 9) * R * C;  out = d2 + (size_t)(z - 9) * R * C; }
  int c0 = blockIdx.x * 32, r0 = blockIdx.y * 32;
  int tx = threadIdx.x & 31, ty = threadIdx.x >> 5;   // 32x8
  #pragma unroll
  for (int i = 0; i < 4; i++) {
    int r = ty + i * 8;
    tile[r][tx] = f2bf(in[(size_t)(r0 + r) * C + c0 + tx]);
  }
  __syncthreads();
  #pragma unroll
  for (int i = 0; i < 4; i++) {
    int c = ty + i * 8;
    out[(size_t)(c0 + c) * R + r0 + tx] = tile[tx][c];
  }
}

// ---- router: logits, softmax, top-1, gate (both banks) + x->bf16 fused ---
__global__ __launch_bounds__(256) void router_kernel(
    const float* __restrict__ x, unsigned short* __restrict__ xb,
    const float* __restrict__ WrS, const float* __restrict__ brS,
    const float* __restrict__ WrF, const float* __restrict__ brF,
    int* __restrict__ expS, float* __restrict__ gateS,
    int* __restrict__ expF, float* __restrict__ gateF) {
  __shared__ float wS[DIMD * NE], wF[DIMD * NE];
  for (int i = threadIdx.x; i < DIMD * NE / 4; i += 256) {
    ((float4*)wS)[i] = ((const float4*)WrS)[i];
    ((float4*)wF)[i] = ((const float4*)WrF)[i];
  }
  __syncthreads();
  const int w = threadIdx.x >> 6, lane = threadIdx.x & 63;
  const int n0 = (blockIdx.x * 4 + w) * 8;       // 8 tokens per wave
  for (int t = 0; t < 8; t++) {
    const int n = n0 + t;
    const float* xr = x + (size_t)n * DIMD + lane * 8;
    float4 xa = *(const float4*)xr, xb4 = *(const float4*)(xr + 4);
    float xv[8] = {xa.x, xa.y, xa.z, xa.w, xb4.x, xb4.y, xb4.z, xb4.w};
    u16x8 xo;
    #pragma unroll
    for (int j = 0; j < 8; j++) xo[j] = f2bf(xv[j]);
    *(u16x8*)(xb + (size_t)n * DIMD + lane * 8) = xo;   // fused x->bf16
    float aS[NE], aF[NE];
    #pragma unroll
    for (int e = 0; e < NE; e++) { aS[e] = 0.f; aF[e] = 0.f; }
    #pragma unroll
    for (int j = 0; j < 8; j++) {
      const int k = lane * 8 + j;
      const float* ps = &wS[k * NE];
      const float* pf = &wF[k * NE];
      #pragma unroll
      for (int e = 0; e < NE; e++) { aS[e] += xv[j] * ps[e]; aF[e] += xv[j] * pf[e]; }
    }
    #pragma unroll
    for (int e = 0; e < NE; e++)
      for (int off = 32; off; off >>= 1) {
        aS[e] += __shfl_xor(aS[e], off);
        aF[e] += __shfl_xor(aF[e], off);
      }
    if (lane == 0) {
      float l[NE];
      #pragma unroll
      for (int e = 0; e < NE; e++) l[e] = aS[e] + brS[e];
      float m = l[0]; int am = 0;
      #pragma unroll
      for (int e = 1; e < NE; e++) if (l[e] > m) { m = l[e]; am = e; }  // first max
      float s = 0.f;
      #pragma unroll
      for (int e = 0; e < NE; e++) s += __expf(l[e] - m);
      expS[n] = am; gateS[n] = __builtin_amdgcn_rcpf(s);
      #pragma unroll
      for (int e = 0; e < NE; e++) l[e] = aF[e] + brF[e];
      m = l[0]; am = 0;
      #pragma unroll
      for (int e = 1; e < NE; e++) if (l[e] > m) { m = l[e]; am = e; }
      s = 0.f;
      #pragma unroll
      for (int e = 0; e < NE; e++) s += __expf(l[e] - m);
      expF[n] = am; gateF[n] = __builtin_amdgcn_rcpf(s);
    }
  }
}

// ------------- parallel stable capacity scan (3 kernels) ------------------
__global__ __launch_bounds__(256) void scan_count_kernel(
    const int* __restrict__ expS, const int* __restrict__ expF,
    int* __restrict__ blockcnt) {
  const int b = blockIdx.x, t = threadIdx.x;
  const int w = t >> 6, lane = t & 63;
  const int eS_ = expS[b * 256 + t], eF_ = expF[b * 256 + t];
  __shared__ int cnt[2][4][NE];
  #pragma unroll
  for (int q = 0; q < NE; q++) {
    unsigned long long mS = __ballot(eS_ == q);
    unsigned long long mF = __ballot(eF_ == q);
    if (lane == 0) { cnt[0][w][q] = __popcll(mS); cnt[1][w][q] = __popcll(mF); }
  }
  __syncthreads();
  if (t < 16) {
    const int bank = t >> 3, q = t & 7;
    blockcnt[bank * NBLK * NE + b * NE + q] =
        cnt[bank][0][q] + cnt[bank][1][q] + cnt[bank][2][q] + cnt[bank][3][q];
  }
}

// meta layout: [cntS 8][hbS 8][cntF 8][hbF 8]; hidden bases 128-aligned
__global__ __launch_bounds__(64) void scan_base_kernel(
    const int* __restrict__ blockcnt, int* __restrict__ blockbase,
    int* __restrict__ meta) {
  __shared__ int tot[2][NE];
  const int t = threadIdx.x;
  if (t < 16) {
    const int bank = t >> 3, q = t & 7;
    int run = 0;
    for (int i = 0; i < NBLK; i++) {
      int v = blockcnt[bank * NBLK * NE + i * NE + q];
      blockbase[bank * NBLK * NE + i * NE + q] = run;
      run += v;
    }
    tot[bank][q] = run;
  }
  __syncthreads();
  if (t == 0) {
    int hb_ = 0;
    for (int q = 0; q < NE; q++) {
      int cc = tot[0][q]; if (cc > CAPQ) cc = CAPQ;
      meta[q] = cc; meta[NE + q] = hb_;
      hb_ += ((cc + 127) >> 7) << 7;          // 128-aligned hidden base
    }
    hb_ = 0;
    for (int q = 0; q < NE; q++) {
      int cc = tot[1][q]; if (cc > CAPQ) cc = CAPQ;
      meta[2 * NE + q] = cc; meta[3 * NE + q] = hb_;
      hb_ += ((cc + 127) >> 7) << 7;
    }
  }
}

__global__ __launch_bounds__(256) void scan_write_kernel(
    const int* __restrict__ expS, const int* __restrict__ expF,
    const int* __restrict__ blockbase,
    int* __restrict__ idxS, int* __restrict__ idxF) {
  const int b = blockIdx.x, t = threadIdx.x;
  const int w = t >> 6, lane = t & 63;
  const int n = b * 256 + t;
  const int eS_ = expS[n], eF_ = expF[n];
  __shared__ int wcnt[2][4][NE];
  const unsigned long long ltmask = ((unsigned long long)1 << lane) - 1;
  int rS = 0, rF = 0;
  #pragma unroll
  for (int q = 0; q < NE; q++) {
    unsigned long long mS = __ballot(eS_ == q);
    unsigned long long mF = __ballot(eF_ == q);
    if (eS_ == q) rS = __popcll(mS & ltmask);
    if (eF_ == q) rF = __popcll(mF & ltmask);
    if (lane == 0) { wcnt[0][w][q] = __popcll(mS); wcnt[1][w][q] = __popcll(mF); }
  }
  __syncthreads();
  int pS = blockbase[0 * NBLK * NE + b * NE + eS_] + rS;
  int pF = blockbase[1 * NBLK * NE + b * NE + eF_] + rF;
  #pragma unroll
  for (int wv = 0; wv < 4; wv++) {
    if (wv < w) { pS += wcnt[0][wv][eS_]; pF += wcnt[1][wv][eF_]; }
  }
  if (pS < CAPQ) idxS[eS_ * CAPQ + pS] = n;
  if (pF < CAPQ) idxF[eF_ * CAPQ + pF] = n;
}

// --- MFMA GEMM, 128x128 tile, BK=32, 8 waves (4x2), dbuf, 32 KB LDS ------
// LDS 32 KB/block -> 4 blocks/CU, 32 waves/CU (full). TLP from 4 independent
// blocks hides per-tile latency (m97/m114 mechanism). Counted vmcnt(2):
// tile t+1's 2 loads stay in flight across tile t's gate. BK=32 swizzle
// (R9-correctness-proven): stored chunk = chunk ^ ((row>>1)&3), source
// pre-swizzle gch = (tid&3)^((tid>>3)&3); balanced 8 lanes/16B-slot -> 0 conf.
// EPI 0: C = gelu(A@Bt^T + bias) -> hidden bf16     (K=DIMD, NC=FFD)
// EPI 1: out = A@Bt^T + bias (f32 write)            (K=FFD,  NC=DIMD)
// EPI 2: out[tok] += (A@Bt^T + bias) * gate[tok]    (K=FFD,  NC=DIMD)
template <int EPI, bool GATHER, bool BANKED>
__global__ __launch_bounds__(512, 8) void gemm_kernel(
    const unsigned short* __restrict__ A,
    const unsigned short* __restrict__ Bt,   // [(e)][NC][K] bf16 (pre-transposed)
    const float* __restrict__ bias,          // [(e)][NC]
    const int* __restrict__ idx, const int* __restrict__ cnt,
    const int* __restrict__ hb, const float* __restrict__ gate,
    unsigned short* __restrict__ hidOut, float* __restrict__ fOut) {
  constexpr int K  = (EPI == 0) ? DIMD : FFD;
  constexpr int NC = (EPI == 0) ? FFD : DIMD;
  constexpr int NT = K / 32;                  // 16 (FFN1) or 64 (FFN2)

  __shared__ __align__(16) unsigned short lA[2][128 * 32];  // 2 x 8 KiB
  __shared__ __align__(16) unsigned short lB[2][128 * 32];  // 2 x 8 KiB

  const int tid = threadIdx.x;
  const int w = tid >> 6, lane = tid & 63;

  // bijective XCD-chunked block swizzle (m204)
  const int gx = gridDim.x;
  const int nwg = gx * gridDim.y;
  int flat = blockIdx.y * gx + blockIdx.x;
  {
    const int q8 = nwg >> 3, r8 = nwg & 7;
    const int xcd = flat & 7, loc = flat >> 3;
    flat = (xcd < r8 ? xcd * (q8 + 1) : r8 * (q8 + 1) + (xcd - r8) * q8) + loc;
  }
  const int bx = flat % gx, by = flat / gx;

  int e = 0, r0, cnte = 0;
  if (BANKED) {
    e = by / TPE;
    r0 = (by - e * TPE) * 128;
    cnte = cnt[e];
    if (r0 >= cnte) return;
  } else {
    r0 = by * 128;
  }

  // --- staging: thread covers row tid>>2, pre-swizzled 16B chunk gch
  const int srow = tid >> 2;                       // 0..127
  const int gch  = (tid & 3) ^ ((tid >> 3) & 3);   // inverse of read swizzle
  const unsigned short* aSrc;
  const unsigned short* bSrc;
  const size_t bcol0 = (size_t)(BANKED ? e * NC : 0) + (size_t)bx * 128;
  {
    size_t arow;
    if (GATHER) {
      int s = r0 + srow;
      int tok = (s < cnte) ? idx[e * CAPQ + s] : 0;
      arow = (size_t)tok;
    } else if (BANKED) {
      arow = (size_t)(hb[e] + r0 + srow);
    } else {
      arow = (size_t)(r0 + srow);
    }
    aSrc = A + arow * K + gch * 8;
    bSrc = Bt + (bcol0 + srow) * K + gch * 8;
  }

  f32x4 acc[2][4];
  #pragma unroll
  for (int m = 0; m < 2; m++)
    #pragma unroll
    for (int n = 0; n < 4; n++) acc[m][n] = (f32x4){0.f, 0.f, 0.f, 0.f};

  const int wr = w >> 1, wc = w & 1;       // wave: rows wr*32.., cols wc*64..
  const int grp = lane >> 4, l15 = lane & 15;
  const int kch = grp ^ ((l15 >> 1) & 3);  // swizzled k-chunk (R9-proven)
  const int aBase = (wr * 32 + l15) * 32 + kch * 8;   // ushort index
  const int bBase = (wc * 64 + l15) * 32 + kch * 8;

  auto stage = [&](int buf, int k0) {
    char* la = (char*)&lA[buf][0] + (unsigned)w * 1024;
    char* lb = (char*)&lB[buf][0] + (unsigned)w * 1024;
    GLL16(aSrc + k0, la);
    GLL16(bSrc + k0, lb);
  };

  stage(0, 0);                                 // 2 loads in flight
  int cur = 0;
  #pragma unroll 1
  for (int t = 0; t < NT; t++) {
    if (t + 1 < NT) {
      stage(cur ^ 1, (t + 1) * 32);            // +2 loads (4 in flight)
      asm volatile("s_waitcnt vmcnt(2)" ::: "memory");   // tile t landed
    } else {
      asm volatile("s_waitcnt vmcnt(0)" ::: "memory");   // last tile drains
    }
    __builtin_amdgcn_s_barrier();              // publish tile t across waves
    __builtin_amdgcn_sched_barrier(0);
    const unsigned short* A_ = &lA[cur][0];
    const unsigned short* B_ = &lB[cur][0];
    bf16x8 af[2], bfv[4];
    #pragma unroll
    for (int m = 0; m < 2; m++) af[m] = *(const bf16x8*)&A_[aBase + m * 512];
    #pragma unroll
    for (int n = 0; n < 4; n++) bfv[n] = *(const bf16x8*)&B_[bBase + n * 512];
    __builtin_amdgcn_s_setprio(1);
    #pragma unroll
    for (int m = 0; m < 2; m++)
      #pragma unroll
      for (int n = 0; n < 4; n++)
        acc[m][n] = __builtin_amdgcn_mfma_f32_16x16x32_bf16(af[m], bfv[n], acc[m][n], 0, 0, 0);
    __builtin_amdgcn_s_setprio(0);
    __builtin_amdgcn_sched_barrier(0);
    __builtin_amdgcn_s_barrier();              // all waves done reading buf[cur]
    cur ^= 1;
  }

  // --- epilogue: C/D layout col=lane&15, row=(lane>>4)*4+j (m89-verified)
  const int grp4 = grp * 4;
  if constexpr (EPI == 0) {
    const size_t hrow0 = (size_t)((BANKED ? hb[e] : 0) + r0);
    const float* bP2 = bias + (BANKED ? e * NC : 0) + bx * 128;
    #pragma unroll
    for (int m = 0; m < 2; m++)
      #pragma unroll
      for (int j = 0; j < 4; j++) {
        const int rloc = wr * 32 + m * 16 + grp4 + j;
        unsigned short* hrow = hidOut + (hrow0 + rloc) * FFD + bx * 128;
        #pragma unroll
        for (int n = 0; n < 4; n++) {
          const int cloc = wc * 64 + n * 16 + l15;
          float v = acc[m][n][j] + bP2[cloc];
          hrow[cloc] = f2bf(gelu_f(v));
        }
      }
  } else if constexpr (EPI == 1) {
    const float* bP2 = bias + bx * 128;
    #pragma unroll
    for (int m = 0; m < 2; m++)
      #pragma unroll
      for (int j = 0; j < 4; j++) {
        const int rloc = wr * 32 + m * 16 + grp4 + j;
        float* orow = fOut + (size_t)(r0 + rloc) * DIMD + bx * 128;
        #pragma unroll
        for (int n = 0; n < 4; n++) {
          const int cloc = wc * 64 + n * 16 + l15;
          orow[cloc] = acc[m][n][j] + bP2[cloc];
        }
      }
  } else {
    const float* bP2 = bias + e * NC + bx * 128;
    const int* idxe = idx + e * CAPQ + r0;
    #pragma unroll
    for (int m = 0; m < 2; m++)
      #pragma unroll
      for (int j = 0; j < 4; j++) {
        const int rloc = wr * 32 + m * 16 + grp4 + j;
        if (r0 + rloc < cnte) {
          const int tok = idxe[rloc];
          const float gv = gate[tok];
          float* orow = fOut + (size_t)tok * DIMD + bx * 128;
          #pragma unroll
          for (int n = 0; n < 4; n++) {
            const int cloc = wc * 64 + n * 16 + l15;
            orow[cloc] += (acc[m][n][j] + bP2[cloc]) * gv;  // unique (tok,col)
          }
        }
      }
  }
}

extern "C" void kernel_launch(void* const* d_in, const int* in_sizes, int n_in,
                              void* d_out, int out_size, void* d_ws, size_t ws_size,
                              hipStream_t stream) {
  const float* x   = (const float*)d_in[0];
  const float* WrS = (const float*)d_in[1];
  const float* brS = (const float*)d_in[2];
  const float* WrF = (const float*)d_in[3];
  const float* brF = (const float*)d_in[4];
  const float* Ws1 = (const float*)d_in[5];
  const float* bs1 = (const float*)d_in[6];
  const float* Ws2 = (const float*)d_in[7];
  const float* bs2 = (const float*)d_in[8];
  const float* W1s = (const float*)d_in[9];
  const float* b1s = (const float*)d_in[10];
  const float* W2s = (const float*)d_in[11];
  const float* b2s = (const float*)d_in[12];
  const float* W1f = (const float*)d_in[13];
  const float* b1f = (const float*)d_in[14];
  const float* W2f = (const float*)d_in[15];
  const float* b2f = (const float*)d_in[16];
  float* out = (float*)d_out;

  char* ws = (char*)d_ws;
  size_t off = 0;
  auto alloc = [&](size_t b) { char* p = ws + off; off += (b + 255) & ~(size_t)255; return p; };
  unsigned short* xb     = (unsigned short*)alloc((size_t)N_TOK * DIMD * 2);
  unsigned short* ws1t   = (unsigned short*)alloc((size_t)FFD * DIMD * 2);
  unsigned short* ws2t   = (unsigned short*)alloc((size_t)DIMD * FFD * 2);
  unsigned short* w1st   = (unsigned short*)alloc((size_t)NE * FFD * DIMD * 2);
  unsigned short* w2st   = (unsigned short*)alloc((size_t)NE * DIMD * FFD * 2);
  unsigned short* w1ft   = (unsigned short*)alloc((size_t)NE * FFD * DIMD * 2);
  unsigned short* w2ft   = (unsigned short*)alloc((size_t)NE * DIMD * FFD * 2);
  unsigned short* hidden = (unsigned short*)alloc((size_t)(N_TOK + NE * 128) * FFD * 2);
  int*   expS = (int*)alloc((size_t)N_TOK * 4);
  int*   expF = (int*)alloc((size_t)N_TOK * 4);
  float* gS   = (float*)alloc((size_t)N_TOK * 4);
  float* gF   = (float*)alloc((size_t)N_TOK * 4);
  int*   idxS = (int*)alloc((size_t)NE * CAPQ * 4);
  int*   idxF = (int*)alloc((size_t)NE * CAPQ * 4);
  int*   meta = (int*)alloc(4 * NE * 4);
  int*   blockcnt  = (int*)alloc((size_t)2 * NBLK * NE * 4);
  int*   blockbase = (int*)alloc((size_t)2 * NBLK * NE * 4);
  if (off > ws_size) return;   // ws too small -> will fail validation

  int* cntS = meta;           int* hbS = meta + NE;
  int* cntF = meta + 2 * NE;  int* hbF = meta + 3 * NE;

  // merged weight transposes (2 launches instead of 6)
  transpose_cvt3_kernel<<<dim3(FFD / 32, DIMD / 32, 17), 256, 0, stream>>>(
      Ws1, W1s, W1f, ws1t, w1st, w1ft, DIMD, FFD);
  transpose_cvt3_kernel<<<dim3(DIMD / 32, FFD / 32, 17), 256, 0, stream>>>(
      Ws2, W2s, W2f, ws2t, w2st, w2ft, FFD, DIMD);
  router_kernel<<<N_TOK / 32, 256, 0, stream>>>(x, xb, WrS, brS, WrF, brF, expS, gS, expF, gF);
  scan_count_kernel<<<NBLK, 256, 0, stream>>>(expS, expF, blockcnt);
  scan_base_kernel<<<1, 64, 0, stream>>>(blockcnt, blockbase, meta);
  scan_write_kernel<<<NBLK, 256, 0, stream>>>(expS, expF, blockbase, idxS, idxF);

  // shared FFN (writes all of out)
  gemm_kernel<0, false, false><<<dim3(FFD / 128, N_TOK / 128), 512, 0, stream>>>(
      xb, ws1t, bs1, nullptr, nullptr, nullptr, nullptr, hidden, nullptr);
  gemm_kernel<1, false, false><<<dim3(DIMD / 128, N_TOK / 128), 512, 0, stream>>>(
      hidden, ws2t, bs2, nullptr, nullptr, nullptr, nullptr, nullptr, out);
  // spatial bank (adds into out)
  gemm_kernel<0, true, true><<<dim3(FFD / 128, NE * TPE), 512, 0, stream>>>(
      xb, w1st, b1s, idxS, cntS, hbS, nullptr, hidden, nullptr);
  gemm_kernel<2, false, true><<<dim3(DIMD / 128, NE * TPE), 512, 0, stream>>>(
      hidden, w2st, b2s, idxS, cntS, hbS, gS, nullptr, out);
  // spectral bank (adds into out)
  gemm_kernel<0, true, true><<<dim3(FFD / 128, NE * TPE), 512, 0, stream>>>(
      xb, w1ft, b1f, idxF, cntF, hbF, nullptr, hidden, nullptr);
  gemm_kernel<2, false, true><<<dim3(DIMD / 128, NE * TPE), 512, 0, stream>>>(
      hidden, w2ft, b2f, idxF, cntF, hbF, gF, nullptr, out);
}

// Round 11
// 786.729 us; speedup vs baseline: 1.2781x; 1.0890x over previous
//
#include <hip/hip_runtime.h>
#include <hip/hip_bf16.h>
#include <math.h>

// Problem constants
#define N_TOK 32768
#define DIMD  512
#define FFD   2048
#define NE    8
#define CAPQ  5120
#define TPE   40          // CAPQ / 128 row-tiles per expert
#define NBLK  128         // scan blocks (256 tokens each)
#define HROWS_BANK (N_TOK + NE * 128)   // 33792 rows per bank hidden region

typedef __attribute__((ext_vector_type(8))) short          bf16x8;
typedef __attribute__((ext_vector_type(4))) float          f32x4;
typedef __attribute__((ext_vector_type(8))) unsigned short u16x8;

__device__ __forceinline__ unsigned short f2bf(float f) {
  union { float f; unsigned u; } v; v.f = f;
  unsigned r = v.u + 0x7fffu + ((v.u >> 16) & 1u);   // RNE (finite values only)
  return (unsigned short)(r >> 16);
}

// tanh-gelu in sigmoid form: 0.5v(1+tanh u) == v * sigma(2u), exact identity.
__device__ __forceinline__ float gelu_f(float v) {
  float t = v * v;
  float q = fmaf(-0.0713548162f, t, -1.5957691216f);   // -2*(a + b*t)
  float w = v * q;                                      // -2u
  float d = 1.0f + __expf(w);
  return v * __builtin_amdgcn_rcpf(d);
}

// async global->LDS, 16B/lane; LDS dest is wave-uniform base + lane*16
#define GLL16(gsrc, ldst)                                                      \
  __builtin_amdgcn_global_load_lds(                                            \
      (const __attribute__((address_space(1))) void*)(gsrc),                   \
      (__attribute__((address_space(3))) void*)(ldst), 16, 0, 0)

// ---- merged tiled transpose + f32->bf16: 17 slabs (1 shared + 8 + 8) -----
__global__ __launch_bounds__(256) void transpose_cvt3_kernel(
    const float* __restrict__ s0, const float* __restrict__ s1,
    const float* __restrict__ s2,
    unsigned short* __restrict__ d0, unsigned short* __restrict__ d1,
    unsigned short* __restrict__ d2, int R, int C) {
  __shared__ unsigned short tile[32][33];
  const int z = blockIdx.z;
  const float* in; unsigned short* out;
  if (z == 0)      { in = s0;                            out = d0; }
  else if (z <= 8) { in = s1 + (size_t)(z - 1) * R * C;  out = d1 + (size_t)(z - 1) * R * C; }
  else             { in = s2 + (size_t)(z - 9) * R * C;  out = d2 + (size_t)(z - 9) * R * C; }
  int c0 = blockIdx.x * 32, r0 = blockIdx.y * 32;
  int tx = threadIdx.x & 31, ty = threadIdx.x >> 5;   // 32x8
  #pragma unroll
  for (int i = 0; i < 4; i++) {
    int r = ty + i * 8;
    tile[r][tx] = f2bf(in[(size_t)(r0 + r) * C + c0 + tx]);
  }
  __syncthreads();
  #pragma unroll
  for (int i = 0; i < 4; i++) {
    int c = ty + i * 8;
    out[(size_t)(c0 + c) * R + r0 + tx] = tile[tx][c];
  }
}

// ---- router: logits, softmax, top-1, gate (both banks) + x->bf16 fused ---
__global__ __launch_bounds__(256) void router_kernel(
    const float* __restrict__ x, unsigned short* __restrict__ xb,
    const float* __restrict__ WrS, const float* __restrict__ brS,
    const float* __restrict__ WrF, const float* __restrict__ brF,
    int* __restrict__ expS, float* __restrict__ gateS,
    int* __restrict__ expF, float* __restrict__ gateF) {
  __shared__ float wS[DIMD * NE], wF[DIMD * NE];
  for (int i = threadIdx.x; i < DIMD * NE / 4; i += 256) {
    ((float4*)wS)[i] = ((const float4*)WrS)[i];
    ((float4*)wF)[i] = ((const float4*)WrF)[i];
  }
  __syncthreads();
  const int w = threadIdx.x >> 6, lane = threadIdx.x & 63;
  const int n0 = (blockIdx.x * 4 + w) * 8;       // 8 tokens per wave
  for (int t = 0; t < 8; t++) {
    const int n = n0 + t;
    const float* xr = x + (size_t)n * DIMD + lane * 8;
    float4 xa = *(const float4*)xr, xb4 = *(const float4*)(xr + 4);
    float xv[8] = {xa.x, xa.y, xa.z, xa.w, xb4.x, xb4.y, xb4.z, xb4.w};
    u16x8 xo;
    #pragma unroll
    for (int j = 0; j < 8; j++) xo[j] = f2bf(xv[j]);
    *(u16x8*)(xb + (size_t)n * DIMD + lane * 8) = xo;   // fused x->bf16
    float aS[NE], aF[NE];
    #pragma unroll
    for (int e = 0; e < NE; e++) { aS[e] = 0.f; aF[e] = 0.f; }
    #pragma unroll
    for (int j = 0; j < 8; j++) {
      const int k = lane * 8 + j;
      const float* ps = &wS[k * NE];
      const float* pf = &wF[k * NE];
      #pragma unroll
      for (int e = 0; e < NE; e++) { aS[e] += xv[j] * ps[e]; aF[e] += xv[j] * pf[e]; }
    }
    #pragma unroll
    for (int e = 0; e < NE; e++)
      for (int off = 32; off; off >>= 1) {
        aS[e] += __shfl_xor(aS[e], off);
        aF[e] += __shfl_xor(aF[e], off);
      }
    if (lane == 0) {
      float l[NE];
      #pragma unroll
      for (int e = 0; e < NE; e++) l[e] = aS[e] + brS[e];
      float m = l[0]; int am = 0;
      #pragma unroll
      for (int e = 1; e < NE; e++) if (l[e] > m) { m = l[e]; am = e; }  // first max
      float s = 0.f;
      #pragma unroll
      for (int e = 0; e < NE; e++) s += __expf(l[e] - m);
      expS[n] = am; gateS[n] = __builtin_amdgcn_rcpf(s);
      #pragma unroll
      for (int e = 0; e < NE; e++) l[e] = aF[e] + brF[e];
      m = l[0]; am = 0;
      #pragma unroll
      for (int e = 1; e < NE; e++) if (l[e] > m) { m = l[e]; am = e; }
      s = 0.f;
      #pragma unroll
      for (int e = 0; e < NE; e++) s += __expf(l[e] - m);
      expF[n] = am; gateF[n] = __builtin_amdgcn_rcpf(s);
    }
  }
}

// ------------- parallel stable capacity scan (3 kernels) ------------------
__global__ __launch_bounds__(256) void scan_count_kernel(
    const int* __restrict__ expS, const int* __restrict__ expF,
    int* __restrict__ blockcnt) {
  const int b = blockIdx.x, t = threadIdx.x;
  const int w = t >> 6, lane = t & 63;
  const int eS_ = expS[b * 256 + t], eF_ = expF[b * 256 + t];
  __shared__ int cnt[2][4][NE];
  #pragma unroll
  for (int q = 0; q < NE; q++) {
    unsigned long long mS = __ballot(eS_ == q);
    unsigned long long mF = __ballot(eF_ == q);
    if (lane == 0) { cnt[0][w][q] = __popcll(mS); cnt[1][w][q] = __popcll(mF); }
  }
  __syncthreads();
  if (t < 16) {
    const int bank = t >> 3, q = t & 7;
    blockcnt[bank * NBLK * NE + b * NE + q] =
        cnt[bank][0][q] + cnt[bank][1][q] + cnt[bank][2][q] + cnt[bank][3][q];
  }
}

// meta layout: [cntS 8][hbS 8][cntF 8][hbF 8]; hidden bases 128-aligned
__global__ __launch_bounds__(64) void scan_base_kernel(
    const int* __restrict__ blockcnt, int* __restrict__ blockbase,
    int* __restrict__ meta) {
  __shared__ int tot[2][NE];
  const int t = threadIdx.x;
  if (t < 16) {
    const int bank = t >> 3, q = t & 7;
    int run = 0;
    for (int i = 0; i < NBLK; i++) {
      int v = blockcnt[bank * NBLK * NE + i * NE + q];
      blockbase[bank * NBLK * NE + i * NE + q] = run;
      run += v;
    }
    tot[bank][q] = run;
  }
  __syncthreads();
  if (t == 0) {
    int hb_ = 0;
    for (int q = 0; q < NE; q++) {
      int cc = tot[0][q]; if (cc > CAPQ) cc = CAPQ;
      meta[q] = cc; meta[NE + q] = hb_;
      hb_ += ((cc + 127) >> 7) << 7;          // 128-aligned hidden base
    }
    hb_ = 0;
    for (int q = 0; q < NE; q++) {
      int cc = tot[1][q]; if (cc > CAPQ) cc = CAPQ;
      meta[2 * NE + q] = cc; meta[3 * NE + q] = hb_;
      hb_ += ((cc + 127) >> 7) << 7;
    }
  }
}

__global__ __launch_bounds__(256) void scan_write_kernel(
    const int* __restrict__ expS, const int* __restrict__ expF,
    const int* __restrict__ blockbase,
    int* __restrict__ idxS, int* __restrict__ idxF) {
  const int b = blockIdx.x, t = threadIdx.x;
  const int w = t >> 6, lane = t & 63;
  const int n = b * 256 + t;
  const int eS_ = expS[n], eF_ = expF[n];
  __shared__ int wcnt[2][4][NE];
  const unsigned long long ltmask = ((unsigned long long)1 << lane) - 1;
  int rS = 0, rF = 0;
  #pragma unroll
  for (int q = 0; q < NE; q++) {
    unsigned long long mS = __ballot(eS_ == q);
    unsigned long long mF = __ballot(eF_ == q);
    if (eS_ == q) rS = __popcll(mS & ltmask);
    if (eF_ == q) rF = __popcll(mF & ltmask);
    if (lane == 0) { wcnt[0][w][q] = __popcll(mS); wcnt[1][w][q] = __popcll(mF); }
  }
  __syncthreads();
  int pS = blockbase[0 * NBLK * NE + b * NE + eS_] + rS;
  int pF = blockbase[1 * NBLK * NE + b * NE + eF_] + rF;
  #pragma unroll
  for (int wv = 0; wv < 4; wv++) {
    if (wv < w) { pS += wcnt[0][wv][eS_]; pF += wcnt[1][wv][eF_]; }
  }
  if (pS < CAPQ) idxS[eS_ * CAPQ + pS] = n;
  if (pF < CAPQ) idxF[eF_ * CAPQ + pF] = n;
}

// ======= proven R7 GEMM core (128x128, BK=64, 8 waves, dbuf, vmcnt(4)) ====
// Shared device body used by both the generic kernel and the fused-FFN1 one.
struct GemmCtx {
  const unsigned short* aSrc0;   // A row base (chunk 0 of this thread)
  const unsigned short* aSrc1;
  const unsigned short* bSrc0;
  const unsigned short* bSrc1;
};

template <int K>
__device__ __forceinline__ void gemm_core(
    const GemmCtx& cx, unsigned short (*lA)[128 * 64], unsigned short (*lB)[128 * 64],
    int w, int lane, f32x4 (&acc)[2][4],
    int wr, int wc, int grp, int l15) {
  constexpr int NT = K / 64;
  const int swz = l15 & 7;
  int aoff[2], boff[4], kche[2];
  #pragma unroll
  for (int m = 0; m < 2; m++) aoff[m] = (wr * 32 + m * 16 + l15) * 64;
  #pragma unroll
  for (int n = 0; n < 4; n++) boff[n] = (wc * 64 + n * 16 + l15) * 64;
  #pragma unroll
  for (int kk = 0; kk < 2; kk++) kche[kk] = ((kk * 4 + grp) ^ swz) * 8;

  auto stage = [&](int buf, int k0) {
    char* la = (char*)&lA[buf][0] + (unsigned)w * 1024;
    char* lb = (char*)&lB[buf][0] + (unsigned)w * 1024;
    GLL16(cx.aSrc0 + k0, la);
    GLL16(cx.aSrc1 + k0, la + 8192);
    GLL16(cx.bSrc0 + k0, lb);
    GLL16(cx.bSrc1 + k0, lb + 8192);
  };

  stage(0, 0);                                 // 4 loads in flight
  int cur = 0;
  #pragma unroll 1
  for (int t = 0; t < NT; t++) {
    if (t + 1 < NT) {
      stage(cur ^ 1, (t + 1) * 64);            // +4 loads (8 in flight)
      asm volatile("s_waitcnt vmcnt(4)" ::: "memory");   // tile t landed
    } else {
      asm volatile("s_waitcnt vmcnt(0)" ::: "memory");   // last tile drains
    }
    __builtin_amdgcn_s_barrier();              // publish tile t across waves
    __builtin_amdgcn_sched_barrier(0);
    const unsigned short* A_ = &lA[cur][0];
    const unsigned short* B_ = &lB[cur][0];
    #pragma unroll
    for (int kk = 0; kk < 2; kk++) {
      const int co = kche[kk];
      bf16x8 af[2], bfv[4];
      #pragma unroll
      for (int m = 0; m < 2; m++) af[m] = *(const bf16x8*)&A_[aoff[m] + co];
      #pragma unroll
      for (int n = 0; n < 4; n++) bfv[n] = *(const bf16x8*)&B_[boff[n] + co];
      __builtin_amdgcn_s_setprio(1);
      #pragma unroll
      for (int m = 0; m < 2; m++)
        #pragma unroll
        for (int n = 0; n < 4; n++)
          acc[m][n] = __builtin_amdgcn_mfma_f32_16x16x32_bf16(af[m], bfv[n], acc[m][n], 0, 0, 0);
      __builtin_amdgcn_s_setprio(0);
    }
    __builtin_amdgcn_sched_barrier(0);
    __builtin_amdgcn_s_barrier();              // all waves done reading buf[cur]
    cur ^= 1;
  }
}

__device__ __forceinline__ void xcd_swizzle(int gx, int gy, int& bx, int& by) {
  const int nwg = gx * gy;
  int flat = by * gx + bx;
  const int q8 = nwg >> 3, r8 = nwg & 7;
  const int xcd = flat & 7, loc = flat >> 3;
  flat = (xcd < r8 ? xcd * (q8 + 1) : r8 * (q8 + 1) + (xcd - r8) * q8) + loc;
  bx = flat % gx; by = flat / gx;
}

// ---- generic GEMM kernel (FFN1 fallback + all FFN2 paths), R7-identical --
template <int EPI, bool GATHER, bool BANKED>
__global__ __launch_bounds__(512, 4) void gemm_kernel(
    const unsigned short* __restrict__ A,
    const unsigned short* __restrict__ Bt,
    const float* __restrict__ bias,
    const int* __restrict__ idx, const int* __restrict__ cnt,
    const int* __restrict__ hb, const float* __restrict__ gate,
    unsigned short* __restrict__ hidOut, float* __restrict__ fOut) {
  constexpr int K  = (EPI == 0) ? DIMD : FFD;
  constexpr int NC = (EPI == 0) ? FFD : DIMD;

  __shared__ __align__(16) unsigned short lA[2][128 * 64];
  __shared__ __align__(16) unsigned short lB[2][128 * 64];

  const int tid = threadIdx.x;
  const int w = tid >> 6, lane = tid & 63;
  int bx = blockIdx.x, by = blockIdx.y;
  xcd_swizzle(gridDim.x, gridDim.y, bx, by);

  int e = 0, r0, cnte = 0;
  if (BANKED) {
    e = by / TPE;
    r0 = (by - e * TPE) * 128;
    cnte = cnt[e];
    if (r0 >= cnte) return;
  } else {
    r0 = by * 128;
  }

  const int srow = lane >> 3;
  const int sch  = (lane & 7) ^ srow;
  const size_t bcol0 = (size_t)(BANKED ? e * NC : 0) + (size_t)bx * 128;
  GemmCtx cx;
  {
    const int ri0 = (0 * 8 + w) * 8 + srow;
    const int ri1 = (1 * 8 + w) * 8 + srow;
    size_t ar0, ar1;
    if (GATHER) {
      int s0 = r0 + ri0, s1 = r0 + ri1;
      ar0 = (size_t)((s0 < cnte) ? idx[e * CAPQ + s0] : 0);
      ar1 = (size_t)((s1 < cnte) ? idx[e * CAPQ + s1] : 0);
    } else if (BANKED) {
      ar0 = (size_t)(hb[e] + r0 + ri0);
      ar1 = (size_t)(hb[e] + r0 + ri1);
    } else {
      ar0 = (size_t)(r0 + ri0);
      ar1 = (size_t)(r0 + ri1);
    }
    cx.aSrc0 = A + ar0 * K + sch * 8;
    cx.aSrc1 = A + ar1 * K + sch * 8;
    cx.bSrc0 = Bt + (bcol0 + ri0) * K + sch * 8;
    cx.bSrc1 = Bt + (bcol0 + ri1) * K + sch * 8;
  }

  f32x4 acc[2][4];
  #pragma unroll
  for (int m = 0; m < 2; m++)
    #pragma unroll
    for (int n = 0; n < 4; n++) acc[m][n] = (f32x4){0.f, 0.f, 0.f, 0.f};

  const int wr = w >> 1, wc = w & 1;
  const int grp = lane >> 4, l15 = lane & 15;
  gemm_core<K>(cx, lA, lB, w, lane, acc, wr, wc, grp, l15);

  const int grp4 = grp * 4;
  if constexpr (EPI == 0) {
    const size_t hrow0 = (size_t)((BANKED ? hb[e] : 0) + r0);
    const float* bP2 = bias + (BANKED ? e * NC : 0) + bx * 128;
    #pragma unroll
    for (int m = 0; m < 2; m++)
      #pragma unroll
      for (int j = 0; j < 4; j++) {
        const int rloc = wr * 32 + m * 16 + grp4 + j;
        unsigned short* hrow = hidOut + (hrow0 + rloc) * FFD + bx * 128;
        #pragma unroll
        for (int n = 0; n < 4; n++) {
          const int cloc = wc * 64 + n * 16 + l15;
          float v = acc[m][n][j] + bP2[cloc];
          hrow[cloc] = f2bf(gelu_f(v));
        }
      }
  } else if constexpr (EPI == 1) {
    const float* bP2 = bias + bx * 128;
    #pragma unroll
    for (int m = 0; m < 2; m++)
      #pragma unroll
      for (int j = 0; j < 4; j++) {
        const int rloc = wr * 32 + m * 16 + grp4 + j;
        float* orow = fOut + (size_t)(r0 + rloc) * DIMD + bx * 128;
        #pragma unroll
        for (int n = 0; n < 4; n++) {
          const int cloc = wc * 64 + n * 16 + l15;
          orow[cloc] = acc[m][n][j] + bP2[cloc];
        }
      }
  } else {
    const float* bP2 = bias + e * NC + bx * 128;
    const int* idxe = idx + e * CAPQ + r0;
    #pragma unroll
    for (int m = 0; m < 2; m++)
      #pragma unroll
      for (int j = 0; j < 4; j++) {
        const int rloc = wr * 32 + m * 16 + grp4 + j;
        if (r0 + rloc < cnte) {
          const int tok = idxe[rloc];
          const float gv = gate[tok];
          float* orow = fOut + (size_t)tok * DIMD + bx * 128;
          #pragma unroll
          for (int n = 0; n < 4; n++) {
            const int cloc = wc * 64 + n * 16 + l15;
            orow[cloc] += (acc[m][n][j] + bP2[cloc]) * gv;  // unique (tok,col)
          }
        }
      }
  }
}

// ---- fused FFN1: blockIdx.z (+zoff) selects {shared, spatial, spectral} --
// All three write DISJOINT hidden regions (hb1/hb2 row bases) -> independent.
__global__ __launch_bounds__(512, 4) void gemm_ffn1z(
    const unsigned short* __restrict__ xb,
    const unsigned short* __restrict__ ws1t,
    const unsigned short* __restrict__ w1st,
    const unsigned short* __restrict__ w1ft,
    const float* __restrict__ bs1, const float* __restrict__ b1s,
    const float* __restrict__ b1f,
    const int* __restrict__ idxS, const int* __restrict__ cntS,
    const int* __restrict__ hbS,
    const int* __restrict__ idxF, const int* __restrict__ cntF,
    const int* __restrict__ hbF,
    unsigned short* __restrict__ hid,
    long long hb1, long long hb2, int zoff) {
  constexpr int K = DIMD, NC = FFD;

  __shared__ __align__(16) unsigned short lA[2][128 * 64];
  __shared__ __align__(16) unsigned short lB[2][128 * 64];

  const int tid = threadIdx.x;
  const int w = tid >> 6, lane = tid & 63;
  const int z = (int)blockIdx.z + zoff;

  const unsigned short* Bt;
  const float* bias;
  const int *idx = nullptr, *cnt = nullptr, *hb = nullptr;
  long long hidbase;
  bool banked;
  if (z == 0)      { Bt = ws1t; bias = bs1; hidbase = 0;   banked = false; }
  else if (z == 1) { Bt = w1st; bias = b1s; idx = idxS; cnt = cntS; hb = hbS;
                     hidbase = hb1; banked = true; }
  else             { Bt = w1ft; bias = b1f; idx = idxF; cnt = cntF; hb = hbF;
                     hidbase = hb2; banked = true; }

  int bx = blockIdx.x, by = blockIdx.y;
  xcd_swizzle(gridDim.x, gridDim.y, bx, by);

  int e = 0, r0, cnte = 0;
  if (banked) {
    e = by / TPE;
    r0 = (by - e * TPE) * 128;
    cnte = cnt[e];
    if (r0 >= cnte) return;
  } else {
    if (by >= N_TOK / 128) return;      // shared slice uses 256 of 320 rows
    r0 = by * 128;
  }

  const int srow = lane >> 3;
  const int sch  = (lane & 7) ^ srow;
  const size_t bcol0 = (size_t)(banked ? e * NC : 0) + (size_t)bx * 128;
  GemmCtx cx;
  {
    const int ri0 = (0 * 8 + w) * 8 + srow;
    const int ri1 = (1 * 8 + w) * 8 + srow;
    size_t ar0, ar1;
    if (banked) {    // banks gather tokens
      int s0 = r0 + ri0, s1 = r0 + ri1;
      ar0 = (size_t)((s0 < cnte) ? idx[e * CAPQ + s0] : 0);
      ar1 = (size_t)((s1 < cnte) ? idx[e * CAPQ + s1] : 0);
    } else {
      ar0 = (size_t)(r0 + ri0);
      ar1 = (size_t)(r0 + ri1);
    }
    cx.aSrc0 = xb + ar0 * K + sch * 8;
    cx.aSrc1 = xb + ar1 * K + sch * 8;
    cx.bSrc0 = Bt + (bcol0 + ri0) * K + sch * 8;
    cx.bSrc1 = Bt + (bcol0 + ri1) * K + sch * 8;
  }

  f32x4 acc[2][4];
  #pragma unroll
  for (int m = 0; m < 2; m++)
    #pragma unroll
    for (int n = 0; n < 4; n++) acc[m][n] = (f32x4){0.f, 0.f, 0.f, 0.f};

  const int wr = w >> 1, wc = w & 1;
  const int grp = lane >> 4, l15 = lane & 15;
  gemm_core<K>(cx, lA, lB, w, lane, acc, wr, wc, grp, l15);

  const int grp4 = grp * 4;
  const size_t hrow0 = (size_t)(hidbase + (banked ? hb[e] : 0) + r0);
  const float* bP2 = bias + (banked ? e * NC : 0) + bx * 128;
  #pragma unroll
  for (int m = 0; m < 2; m++)
    #pragma unroll
    for (int j = 0; j < 4; j++) {
      const int rloc = wr * 32 + m * 16 + grp4 + j;
      unsigned short* hrow = hid + (hrow0 + rloc) * FFD + bx * 128;
      #pragma unroll
      for (int n = 0; n < 4; n++) {
        const int cloc = wc * 64 + n * 16 + l15;
        float v = acc[m][n][j] + bP2[cloc];
        hrow[cloc] = f2bf(gelu_f(v));
      }
    }
}

extern "C" void kernel_launch(void* const* d_in, const int* in_sizes, int n_in,
                              void* d_out, int out_size, void* d_ws, size_t ws_size,
                              hipStream_t stream) {
  const float* x   = (const float*)d_in[0];
  const float* WrS = (const float*)d_in[1];
  const float* brS = (const float*)d_in[2];
  const float* WrF = (const float*)d_in[3];
  const float* brF = (const float*)d_in[4];
  const float* Ws1 = (const float*)d_in[5];
  const float* bs1 = (const float*)d_in[6];
  const float* Ws2 = (const float*)d_in[7];
  const float* bs2 = (const float*)d_in[8];
  const float* W1s = (const float*)d_in[9];
  const float* b1s = (const float*)d_in[10];
  const float* W2s = (const float*)d_in[11];
  const float* b2s = (const float*)d_in[12];
  const float* W1f = (const float*)d_in[13];
  const float* b1f = (const float*)d_in[14];
  const float* W2f = (const float*)d_in[15];
  const float* b2f = (const float*)d_in[16];
  float* out = (float*)d_out;

  char* ws = (char*)d_ws;
  size_t off = 0;
  auto alloc = [&](size_t b) { char* p = ws + off; off += (b + 255) & ~(size_t)255; return p; };
  unsigned short* xb     = (unsigned short*)alloc((size_t)N_TOK * DIMD * 2);
  unsigned short* ws1t   = (unsigned short*)alloc((size_t)FFD * DIMD * 2);
  unsigned short* ws2t   = (unsigned short*)alloc((size_t)DIMD * FFD * 2);
  unsigned short* w1st   = (unsigned short*)alloc((size_t)NE * FFD * DIMD * 2);
  unsigned short* w2st   = (unsigned short*)alloc((size_t)NE * DIMD * FFD * 2);
  unsigned short* w1ft   = (unsigned short*)alloc((size_t)NE * FFD * DIMD * 2);
  unsigned short* w2ft   = (unsigned short*)alloc((size_t)NE * DIMD * FFD * 2);
  int*   expS = (int*)alloc((size_t)N_TOK * 4);
  int*   expF = (int*)alloc((size_t)N_TOK * 4);
  float* gS   = (float*)alloc((size_t)N_TOK * 4);
  float* gF   = (float*)alloc((size_t)N_TOK * 4);
  int*   idxS = (int*)alloc((size_t)NE * CAPQ * 4);
  int*   idxF = (int*)alloc((size_t)NE * CAPQ * 4);
  int*   meta = (int*)alloc(4 * NE * 4);
  int*   blockcnt  = (int*)alloc((size_t)2 * NBLK * NE * 4);
  int*   blockbase = (int*)alloc((size_t)2 * NBLK * NE * 4);
  unsigned short* hidden = (unsigned short*)(ws + off);   // hidden LAST, tiered
  const size_t remain = (ws_size > off) ? ws_size - off : 0;
  const size_t bytes3 = (size_t)(N_TOK + 2 * HROWS_BANK) * FFD * 2;  // 3-region
  const size_t bytes2 = (size_t)(2 * HROWS_BANK) * FFD * 2;          // 2-region
  const size_t bytes1 = (size_t)HROWS_BANK * FFD * 2;                // 1-region
  const int tier = (remain >= bytes3) ? 3 : (remain >= bytes2) ? 2 : 1;
  if (remain < bytes1) return;   // ws too small -> will fail validation

  int* cntS = meta;           int* hbS = meta + NE;
  int* cntF = meta + 2 * NE;  int* hbF = meta + 3 * NE;

  transpose_cvt3_kernel<<<dim3(FFD / 32, DIMD / 32, 17), 256, 0, stream>>>(
      Ws1, W1s, W1f, ws1t, w1st, w1ft, DIMD, FFD);
  transpose_cvt3_kernel<<<dim3(DIMD / 32, FFD / 32, 17), 256, 0, stream>>>(
      Ws2, W2s, W2f, ws2t, w2st, w2ft, FFD, DIMD);
  router_kernel<<<N_TOK / 32, 256, 0, stream>>>(x, xb, WrS, brS, WrF, brF, expS, gS, expF, gF);
  scan_count_kernel<<<NBLK, 256, 0, stream>>>(expS, expF, blockcnt);
  scan_base_kernel<<<1, 64, 0, stream>>>(blockcnt, blockbase, meta);
  scan_write_kernel<<<NBLK, 256, 0, stream>>>(expS, expF, blockbase, idxS, idxF);

  const dim3 gFFN2sh(DIMD / 128, N_TOK / 128);
  const dim3 gFFN2bk(DIMD / 128, NE * TPE);

  if (tier == 3) {
    // all three FFN1 in ONE dispatch; regions: sh=[0), sp=[N_TOK), fq=[N_TOK+HROWS)
    const long long hb1 = N_TOK, hb2 = N_TOK + HROWS_BANK;
    gemm_ffn1z<<<dim3(FFD / 128, NE * TPE, 3), 512, 0, stream>>>(
        xb, ws1t, w1st, w1ft, bs1, b1s, b1f,
        idxS, cntS, hbS, idxF, cntF, hbF, hidden, hb1, hb2, 0);
    gemm_kernel<1, false, false><<<gFFN2sh, 512, 0, stream>>>(
        hidden, ws2t, bs2, nullptr, nullptr, nullptr, nullptr, nullptr, out);
    gemm_kernel<2, false, true><<<gFFN2bk, 512, 0, stream>>>(
        hidden + (size_t)hb1 * FFD, w2st, b2s, idxS, cntS, hbS, gS, nullptr, out);
    gemm_kernel<2, false, true><<<gFFN2bk, 512, 0, stream>>>(
        hidden + (size_t)hb2 * FFD, w2ft, b2f, idxF, cntF, hbF, gF, nullptr, out);
  } else if (tier == 2) {
    // shared pair first (region reused by banks afterwards), banks FFN1 fused
    gemm_kernel<0, false, false><<<dim3(FFD / 128, N_TOK / 128), 512, 0, stream>>>(
        xb, ws1t, bs1, nullptr, nullptr, nullptr, nullptr, hidden, nullptr);
    gemm_kernel<1, false, false><<<gFFN2sh, 512, 0, stream>>>(
        hidden, ws2t, bs2, nullptr, nullptr, nullptr, nullptr, nullptr, out);
    const long long hb1 = 0, hb2 = HROWS_BANK;
    gemm_ffn1z<<<dim3(FFD / 128, NE * TPE, 2), 512, 0, stream>>>(
        xb, ws1t, w1st, w1ft, bs1, b1s, b1f,
        idxS, cntS, hbS, idxF, cntF, hbF, hidden, hb1, hb2, 1);
    gemm_kernel<2, false, true><<<gFFN2bk, 512, 0, stream>>>(
        hidden, w2st, b2s, idxS, cntS, hbS, gS, nullptr, out);
    gemm_kernel<2, false, true><<<gFFN2bk, 512, 0, stream>>>(
        hidden + (size_t)hb2 * FFD, w2ft, b2f, idxF, cntF, hbF, gF, nullptr, out);
  } else {
    // tier 1: exact R7 sequence, single hidden region reused
    gemm_kernel<0, false, false><<<dim3(FFD / 128, N_TOK / 128), 512, 0, stream>>>(
        xb, ws1t, bs1, nullptr, nullptr, nullptr, nullptr, hidden, nullptr);
    gemm_kernel<1, false, false><<<gFFN2sh, 512, 0, stream>>>(
        hidden, ws2t, bs2, nullptr, nullptr, nullptr, nullptr, nullptr, out);
    gemm_kernel<0, true, true><<<dim3(FFD / 128, NE * TPE), 512, 0, stream>>>(
        xb, w1st, b1s, idxS, cntS, hbS, nullptr, hidden, nullptr);
    gemm_kernel<2, false, true><<<gFFN2bk, 512, 0, stream>>>(
        hidden, w2st, b2s, idxS, cntS, hbS, gS, nullptr, out);
    gemm_kernel<0, true, true><<<dim3(FFD / 128, NE * TPE), 512, 0, stream>>>(
        xb, w1ft, b1f, idxF, cntF, hbF, nullptr, hidden, nullptr);
    gemm_kernel<2, false, true><<<gFFN2bk, 512, 0, stream>>>(
        hidden, w2ft, b2f, idxF, cntF, hbF, gF, nullptr, out);
  }
}